// Round 4
// baseline (124.137 us; speedup 1.0000x reference)
//
#include <hip/hip_runtime.h>

typedef _Float16 half8 __attribute__((ext_vector_type(8)));
typedef _Float16 half4_t __attribute__((ext_vector_type(4)));
typedef __fp16 fp16x2 __attribute__((ext_vector_type(2)));
typedef float float4_t __attribute__((ext_vector_type(4)));
typedef float float2_t __attribute__((ext_vector_type(2)));

#define NT 512           // 8 waves per block
#define SW 32            // samples per wave
#define SBLK 256         // samples per block (8 waves x 32)
#define P 136            // slab row pitch in halfs (272 B: conflict-optimal, 16B-aligned)

// d_ws fp16 element offsets (weights, MFMA-chunk-major, pre-scaled) — unchanged
#define OFF_W1   0       // [128][32] chunk-major, k>=6 zero-padded, x2log2e
#define OFF_W21  4096
#define OFF_W22  20480
#define OFF_WM1  36864
#define OFF_WM2  53248
#define OFF_W4A  69632   // L4 A-frags: chain0=w31 (raw), chain1=w32 x(-log2e)
#define OFF_BIAS 73728   // fp32[640]: b1..bm2, all x2log2e (acc-init values)
#define WS_HELEMS 73728

#define SCL_TANH 2.8853900817779268f   // 2*log2(e)
#define SCL_SIG  -1.4426950408889634f  // -log2(e)

__device__ __forceinline__ float tanh_pre(float a) {
  float e = __builtin_amdgcn_exp2f(a);
  return fmaf(-2.f, __builtin_amdgcn_rcpf(1.f + e), 1.f);
}
__device__ __forceinline__ half4_t pack4(float v0, float v1, float v2, float v3) {
  fp16x2 lo = __builtin_amdgcn_cvt_pkrtz(v0, v1);
  fp16x2 hi = __builtin_amdgcn_cvt_pkrtz(v2, v3);
  half4_t h;
  h[0] = (_Float16)lo[0]; h[1] = (_Float16)lo[1];
  h[2] = (_Float16)hi[0]; h[3] = (_Float16)hi[1];
  return h;
}

__global__ void prepack(const float* __restrict__ w1, const float* __restrict__ w21,
                        const float* __restrict__ w22, const float* __restrict__ wm1,
                        const float* __restrict__ wm2, const float* __restrict__ w31,
                        const float* __restrict__ w32, const float* __restrict__ b1,
                        const float* __restrict__ b21, const float* __restrict__ b22,
                        const float* __restrict__ bm1, const float* __restrict__ bm2,
                        _Float16* __restrict__ ws) {
  const int stride = gridDim.x * blockDim.x;
  for (int i = blockIdx.x * blockDim.x + threadIdx.x; i < WS_HELEMS; i += stride) {
    float v;
    if (i < OFF_W21) {                       // W1: [128][32] chunk-major, KC=4
      int t = i;
      int j = t & 7, c = t >> 3, l16 = c & 15, t1 = c >> 4;
      int k8 = t1 & 3, mt = t1 >> 2;
      int row = mt * 16 + l16, k = k8 * 8 + j;
      v = (k < 6) ? w1[row * 6 + k] * SCL_TANH : 0.f;
    } else if (i < OFF_W4A) {                // four 128x128 chunk-major, KC=16
      int t = i - OFF_W21;
      int m = t >> 14; t &= 16383;
      const float* src = (m == 0) ? w21 : (m == 1) ? w22 : (m == 2) ? wm1 : wm2;
      int j = t & 7, c = t >> 3, l16 = c & 15, t1 = c >> 4;
      int k8 = t1 & 15, mt = t1 >> 4;
      v = src[(mt * 16 + l16) * 128 + k8 * 8 + j] * SCL_TANH;
    } else {                                 // L4 A-frags, 2 chains
      int t = i - OFF_W4A;
      int j = t & 7, r = t >> 3, l16 = r & 15, q = r >> 4;
      int cc = q & 15, chain = q >> 4;
      int k = cc * 8 + j, m = l16;
      if (chain == 0) v = (m < 3) ? w31[m * 128 + k] : 0.f;
      else            v = (m < 2) ? w32[m * 128 + k] * SCL_SIG : 0.f;
    }
    ws[i] = (_Float16)v;
  }
  float* bws = (float*)(ws + OFF_BIAS);
  for (int i = blockIdx.x * blockDim.x + threadIdx.x; i < 640; i += stride) {
    int layer = i >> 7, idx = i & 127;
    const float* src = (layer == 0) ? b1 : (layer == 1) ? b21
                     : (layer == 2) ? b22 : (layer == 3) ? bm1 : bm2;
    bws[i] = src[idx] * SCL_TANH;
  }
}

// ---- cooperative weight staging (global -> LDS, linear copy) ----
__device__ __forceinline__ void stage32(const _Float16* __restrict__ src,
                                        _Float16* __restrict__ dst, int tid) {
#pragma unroll
  for (int i = 0; i < 4; ++i)
    *(half8*)(dst + (i * NT + tid) * 8) = *(const half8*)(src + (i * NT + tid) * 8);
}
__device__ __forceinline__ void stage8(const _Float16* __restrict__ src,
                                       _Float16* __restrict__ dst, int tid) {
  *(half8*)(dst + tid * 8) = *(const half8*)(src + tid * 8);
}

// One 128-feature layer for this wave's 32 samples. Input acts in regs (bIn),
// weights from LDS wb (chunk-major, same formula as ws), bias from LDS bbase.
// tanh fused; output written to the wave's private slab ([32][P] halfs).
__device__ __forceinline__ void layer_big(const _Float16* __restrict__ wb,
                                          const float* __restrict__ bbase,
                                          const half8 (&bIn)[2][4],
                                          _Float16* __restrict__ myslab,
                                          int quad, int l16) {
#pragma unroll
  for (int m = 0; m < 8; ++m) {
    float4_t bv = *(const float4_t*)(bbase + m * 16 + quad * 4);
    float4_t a0 = bv, a1 = bv;
#pragma unroll
    for (int kk = 0; kk < 4; ++kk) {
      half8 A = *(const half8*)(wb + ((m * 16 + kk * 4 + quad) * 16 + l16) * 8);
      a0 = __builtin_amdgcn_mfma_f32_16x16x32_f16(A, bIn[0][kk], a0, 0, 0, 0);
      a1 = __builtin_amdgcn_mfma_f32_16x16x32_f16(A, bIn[1][kk], a1, 0, 0, 0);
    }
    const int fo = m * 16 + quad * 4;
    *(half4_t*)(myslab + l16 * P + fo) =
        pack4(tanh_pre(a0[0]), tanh_pre(a0[1]), tanh_pre(a0[2]), tanh_pre(a0[3]));
    *(half4_t*)(myslab + (16 + l16) * P + fo) =
        pack4(tanh_pre(a1[0]), tanh_pre(a1[1]), tanh_pre(a1[2]), tanh_pre(a1[3]));
  }
}

// Read the wave's slab back as next-layer B-frags (per-wave, no barrier needed).
// Cross-lane RAW within the wave: DS ops execute in wave order; asm waitcnt +
// sched_barrier pins compiler ordering (rule #18).
__device__ __forceinline__ void read_frags(const _Float16* __restrict__ myslab,
                                           half8 (&bOut)[2][4], int quad, int l16) {
  asm volatile("s_waitcnt lgkmcnt(0)" ::: "memory");
  __builtin_amdgcn_sched_barrier(0);
#pragma unroll
  for (int n = 0; n < 2; ++n)
#pragma unroll
    for (int kk = 0; kk < 4; ++kk)
      bOut[n][kk] = *(const half8*)(myslab + (n * 16 + l16) * P + kk * 32 + quad * 8);
}

// Sample-split structure: wave owns 32 samples, computes all 128 features/layer.
// LDS: 2x32KB weight dbuf + 8x8.5KB private act slabs + biases = 137728 B
// -> 1 block/CU, 8 waves (2/SIMD), free-running except 6 weight-rotation barriers.
// __launch_bounds__(512,1): 1 block x 8 waves = 2 waves/SIMD -> 256-VGPR budget.
__global__ __launch_bounds__(NT, 1) void bnet_main(
    const float* __restrict__ x, const float* __restrict__ meang,
    const float* __restrict__ stdg, const float* __restrict__ b31,
    const float* __restrict__ b32, const _Float16* __restrict__ ws,
    float* __restrict__ out) {
  __shared__ __align__(16) _Float16 wb0[16384];           // 32 KB
  __shared__ __align__(16) _Float16 wb1[16384];           // 32 KB
  __shared__ __align__(16) _Float16 slab[8 * SW * P];     // 69632 B
  __shared__ __align__(16) float bbuf[640];               // 2560 B

  const int tid = threadIdx.x;
  const int wv = tid >> 6;
  const int lane = tid & 63;
  const int quad = lane >> 4;
  const int l16 = lane & 15;
  const int s0w = blockIdx.x * SBLK + wv * SW;            // this wave's first sample
  const float* biasF = (const float*)(ws + OFF_BIAS);
  _Float16* myslab = slab + wv * (SW * P);

  // ---- prologue: stage W1 (wb0), W21 (wb1), biases (ALL 640: R3 bug was
  // tid<640 with only 512 threads -> bm2 bias garbage) ----
  stage8(ws + OFF_W1, wb0, tid);
  stage32(ws + OFF_W21, wb1, tid);
  bbuf[tid] = biasF[tid];
  if (tid < 128) bbuf[512 + tid] = biasF[512 + tid];
  __syncthreads();                                        // bar1

  // ---- L1: B built from global x (K=32 zero-padded), 2 n-tiles ----
  half8 xb[2];
#pragma unroll
  for (int n = 0; n < 2; ++n) {
#pragma unroll
    for (int j = 0; j < 8; ++j) xb[n][j] = (_Float16)0.f;
    if (quad == 0) {
      const float* xp = x + (size_t)(s0w + n * 16 + l16) * 6;
      float2_t e0 = *(const float2_t*)(xp);
      float2_t e1 = *(const float2_t*)(xp + 2);
      float2_t e2 = *(const float2_t*)(xp + 4);
      xb[n][0] = (_Float16)e0[0]; xb[n][1] = (_Float16)e0[1];
      xb[n][2] = (_Float16)e1[0]; xb[n][3] = (_Float16)e1[1];
      xb[n][4] = (_Float16)e2[0]; xb[n][5] = (_Float16)e2[1];
    }
  }
#pragma unroll
  for (int m = 0; m < 8; ++m) {
    float4_t bv = *(const float4_t*)(bbuf + m * 16 + quad * 4);
    float4_t a0 = bv, a1 = bv;
    half8 A = *(const half8*)(wb0 + ((m * 4 + quad) * 16 + l16) * 8);
    a0 = __builtin_amdgcn_mfma_f32_16x16x32_f16(A, xb[0], a0, 0, 0, 0);
    a1 = __builtin_amdgcn_mfma_f32_16x16x32_f16(A, xb[1], a1, 0, 0, 0);
    const int fo = m * 16 + quad * 4;
    *(half4_t*)(myslab + l16 * P + fo) =
        pack4(tanh_pre(a0[0]), tanh_pre(a0[1]), tanh_pre(a0[2]), tanh_pre(a0[3]));
    *(half4_t*)(myslab + (16 + l16) * P + fo) =
        pack4(tanh_pre(a1[0]), tanh_pre(a1[1]), tanh_pre(a1[2]), tanh_pre(a1[3]));
  }
  half8 f_h[2][4];
  read_frags(myslab, f_h, quad, l16);                     // h
  __syncthreads();                                        // bar2 (wb0 free)

  stage32(ws + OFF_W22, wb0, tid);
  layer_big(wb1, bbuf + 128, f_h, myslab, quad, l16);     // L21: h -> x21 (slab)
  half8 f_a[2][4];
  read_frags(myslab, f_a, quad, l16);                     // x21
  __syncthreads();                                        // bar3 (wb1 free; W22 visible)

  stage32(ws + OFF_WM1, wb1, tid);
  layer_big(wb0, bbuf + 256, f_h, myslab, quad, l16);     // L22: h -> x22 (slab)
  half8 f_b[2][4];
  read_frags(myslab, f_b, quad, l16);                     // x22
  __syncthreads();                                        // bar4 (wb0 free; WM1 visible)

  stage32(ws + OFF_WM2, wb0, tid);
  layer_big(wb1, bbuf + 384, f_a, myslab, quad, l16);     // LM1: x21 -> xm1 (slab)
  read_frags(myslab, f_a, quad, l16);                     // xm1
  __syncthreads();                                        // bar5 (wb1 free; WM2 visible)

  stage8(ws + OFF_W4A, wb1, tid);
  layer_big(wb0, bbuf + 512, f_b, myslab, quad, l16);     // LM2: x22 -> xm2 (slab)
  read_frags(myslab, f_b, quad, l16);                     // xm2
  __syncthreads();                                        // bar6 (W4A visible)

  // ---- L4 + QP epilogue: both chains, both n-tiles, all waves ----
  {
    half8 A40[4], A41[4];
#pragma unroll
    for (int kk = 0; kk < 4; ++kk) {
      A40[kk] = *(const half8*)(wb1 + ((kk * 4 + quad) * 16 + l16) * 8);
      A41[kk] = *(const half8*)(wb1 + ((16 + kk * 4 + quad) * 16 + l16) * 8);
    }
    float4_t c0[2], c1[2];
#pragma unroll
    for (int n = 0; n < 2; ++n) {
      c0[n] = (float4_t){0.f, 0.f, 0.f, 0.f};
      c1[n] = (float4_t){0.f, 0.f, 0.f, 0.f};
      if (quad == 0) {
        c0[n][0] = b31[0]; c0[n][1] = b31[1]; c0[n][2] = b31[2];
        c1[n][0] = b32[0] * SCL_SIG; c1[n][1] = b32[1] * SCL_SIG;
      }
    }
#pragma unroll
    for (int kk = 0; kk < 4; ++kk) {
#pragma unroll
      for (int n = 0; n < 2; ++n) {
        c0[n] = __builtin_amdgcn_mfma_f32_16x16x32_f16(A40[kk], f_a[n][kk], c0[n], 0, 0, 0);
        c1[n] = __builtin_amdgcn_mfma_f32_16x16x32_f16(A41[kk], f_b[n][kk], c1[n], 0, 0, 0);
      }
    }
    if (quad == 0) {   // rows 0..3 live in lanes 0-15, regs 0-3
      const float m0 = meang[0], m1 = meang[1], m2 = meang[2];
      const float m3 = meang[3], m4 = meang[4], m5 = meang[5];
      const float sd0 = stdg[0], sd1 = stdg[1], sd2 = stdg[2];
      const float sd3 = stdg[3], sd4 = stdg[4], sd5 = stdg[5];
#pragma unroll
      for (int n = 0; n < 2; ++n) {
        const int s = s0w + n * 16 + l16;
        float u0 = -c0[n][0];
        float u1 = -c0[n][1];
        float u2 = -c0[n][2];
        float p0 = 4.f * __builtin_amdgcn_rcpf(1.f + __builtin_amdgcn_exp2f(c1[n][0]));
        float p1 = 4.f * __builtin_amdgcn_rcpf(1.f + __builtin_amdgcn_exp2f(c1[n][1]));
        const float* xp = x + (size_t)s * 6;
        float2_t e0 = *(const float2_t*)(xp);
        float2_t e1 = *(const float2_t*)(xp + 2);
        float2_t e2 = *(const float2_t*)(xp + 4);
        float px = e0[0] * sd0 + m0, vx = e0[1] * sd1 + m1;
        float py = e1[0] * sd2 + m2, vy = e1[1] * sd3 + m3;
        float pz = e2[0] * sd4 + m4, vz = e2[1] * sd5 + m5;
        float dx = px - 10.f, dy = py - 10.f, dz = pz - 9.f;
        float dx2 = dx * dx, dy2 = dy * dy, dz2 = dz * dz;
        float dx3 = dx2 * dx, dy3 = dy2 * dy, dz3 = dz2 * dz;
        float barrier = dx3 * dx + dy3 * dy + dz3 * dz - 2401.f;  // R^4
        float bdot = 4.f * (dx3 * vx + dy3 * vy + dz3 * vz);
        float Lf2b = 12.f * (dx2 * vx * vx + dy2 * vy * vy + dz2 * vz * vz);
        float g0 = -4.f * dx3, g1 = -4.f * dy3, g2 = -4.f * dz3;
        float hv = Lf2b + (p0 + p1) * bdot + p0 * p1 * barrier;
        float Gu = g0 * u0 + g1 * u1 + g2 * u2;
        float GG = g0 * g0 + g1 * g1 + g2 * g2;
        float lam = fmaxf(Gu - hv, 0.f) / GG;
        float* op = out + (size_t)s * 3;
        op[0] = u0 - lam * g0;
        op[1] = u1 - lam * g1;
        op[2] = u2 - lam * g2;
      }
    }
  }
}

extern "C" void kernel_launch(void* const* d_in, const int* in_sizes, int n_in,
                              void* d_out, int out_size, void* d_ws, size_t ws_size,
                              hipStream_t stream) {
  const float* x    = (const float*)d_in[0];
  const float* mean = (const float*)d_in[1];
  const float* stdv = (const float*)d_in[2];
  const float* w1   = (const float*)d_in[3];
  const float* b1   = (const float*)d_in[4];
  const float* w21  = (const float*)d_in[5];
  const float* b21  = (const float*)d_in[6];
  const float* w22  = (const float*)d_in[7];
  const float* b22  = (const float*)d_in[8];
  const float* wm1  = (const float*)d_in[9];
  const float* bm1  = (const float*)d_in[10];
  const float* wm2  = (const float*)d_in[11];
  const float* bm2  = (const float*)d_in[12];
  const float* w31  = (const float*)d_in[13];
  const float* b31  = (const float*)d_in[14];
  const float* w32  = (const float*)d_in[15];
  const float* b32  = (const float*)d_in[16];
  _Float16* ws = (_Float16*)d_ws;
  float* out = (float*)d_out;
  const int batch = in_sizes[0] / 6;

  hipLaunchKernelGGL(prepack, dim3(96), dim3(256), 0, stream,
                     w1, w21, w22, wm1, wm2, w31, w32,
                     b1, b21, b22, bm1, bm2, ws);
  hipLaunchKernelGGL(bnet_main, dim3(batch / SBLK), dim3(NT), 0, stream,
                     x, mean, stdv, b31, b32, (const _Float16*)ws, out);
}